// Round 7
// baseline (226.485 us; speedup 1.0000x reference)
//
#include <hip/hip_runtime.h>
#include <stdint.h>

// SpecAugment: out = x * mask, x:(64,1,4000,128) f32.
// Mask params from jax.random.key(1) (threefry2x32, partitionable path),
// computed in-kernel by 12 threads per block into LDS (fused).
// R7: deep-ILP probe — 10 outstanding float4 loads per lane (was 4),
// grid (50,64). Distinguishes MLP-limited vs structural mixed-R/W limit.

#define RATE 0.5f
#define POLICY 3
#define FREQ_MASK 15
#define TIME_MASK 35
#define B 64
#define T 4000
#define F 128
#define PER_BATCH (T * F / 4)   // 128000 float4
#define ITERS 10
#define BLK_CHUNK (ITERS * 256) // 2560 float4 per block
// grid.x = 128000 / 2560 = 50; t-rows per block = 2560/32 = 80

typedef float f32x4 __attribute__((ext_vector_type(4)));

__device__ __forceinline__ uint32_t rotl32(uint32_t x, int r) {
  return (x << r) | (x >> (32 - r));
}

// Standard Threefry-2x32, 20 rounds (JAX's threefry2x32_p). Verified exact R1.
__device__ __forceinline__ void threefry2x32(uint32_t k0, uint32_t k1,
                                             uint32_t x0, uint32_t x1,
                                             uint32_t* o0, uint32_t* o1) {
  const uint32_t ks2 = k0 ^ k1 ^ 0x1BD11BDAu;
  x0 += k0; x1 += k1;
  x0 += x1; x1 = rotl32(x1, 13); x1 ^= x0;
  x0 += x1; x1 = rotl32(x1, 15); x1 ^= x0;
  x0 += x1; x1 = rotl32(x1, 26); x1 ^= x0;
  x0 += x1; x1 = rotl32(x1,  6); x1 ^= x0;
  x0 += k1; x1 += ks2 + 1u;
  x0 += x1; x1 = rotl32(x1, 17); x1 ^= x0;
  x0 += x1; x1 = rotl32(x1, 29); x1 ^= x0;
  x0 += x1; x1 = rotl32(x1, 16); x1 ^= x0;
  x0 += x1; x1 = rotl32(x1, 24); x1 ^= x0;
  x0 += ks2; x1 += k0 + 2u;
  x0 += x1; x1 = rotl32(x1, 13); x1 ^= x0;
  x0 += x1; x1 = rotl32(x1, 15); x1 ^= x0;
  x0 += x1; x1 = rotl32(x1, 26); x1 ^= x0;
  x0 += x1; x1 = rotl32(x1,  6); x1 ^= x0;
  x0 += k0; x1 += k1 + 3u;
  x0 += x1; x1 = rotl32(x1, 17); x1 ^= x0;
  x0 += x1; x1 = rotl32(x1, 29); x1 ^= x0;
  x0 += x1; x1 = rotl32(x1, 16); x1 ^= x0;
  x0 += x1; x1 = rotl32(x1, 24); x1 ^= x0;
  x0 += k1; x1 += ks2 + 4u;
  x0 += x1; x1 = rotl32(x1, 13); x1 ^= x0;
  x0 += x1; x1 = rotl32(x1, 15); x1 ^= x0;
  x0 += x1; x1 = rotl32(x1, 26); x1 ^= x0;
  x0 += x1; x1 = rotl32(x1,  6); x1 ^= x0;
  x0 += ks2; x1 += k0 + 5u;
  *o0 = x0; *o1 = x1;
}

__device__ __forceinline__ float bits_to_uniform(uint32_t bits) {
  uint32_t fb = (bits >> 9) | 0x3f800000u;
  float f = __uint_as_float(fb) - 1.0f;
  return fmaxf(f, 0.0f);
}

// grid = (50, 64), block = 256. Each thread: 10 float4 (block chunk 40 KB).
// Threads 0..11 compute the 12 uniform draws for batch b into LDS.
__global__ __launch_bounds__(256) void specaug_kernel(
    const f32x4* __restrict__ x, f32x4* __restrict__ out) {
  __shared__ float us[12];
  const int b = blockIdx.y;
  const int tid = threadIdx.x;

  // ---- issue ALL 10 loads first (deep MLP; in flight during PRNG) ----
  const size_t base = (size_t)b * PER_BATCH + (size_t)blockIdx.x * BLK_CHUNK + tid;
  f32x4 vv[ITERS];
#pragma unroll
  for (int i = 0; i < ITERS; ++i) vv[i] = x[base + i * 256];

  // ---- 12 threads: subkey d = enc(key1,(0,d)); draw = enc(subkey,(0,b*3+p)) ----
  if (tid < 12) {
    const int d = tid / 3;          // draw kind
    const int p = tid - d * 3;      // policy
    uint32_t k0, k1, o0, o1;
    threefry2x32(0u, 1u, 0u, (uint32_t)d, &k0, &k1);
    threefry2x32(k0, k1, 0u, (uint32_t)(b * 3 + p), &o0, &o1);
    us[tid] = bits_to_uniform(o0 ^ o1);
  }
  __syncthreads();

  // ---- band boundaries (empty band encoded as start==length) ----
  int tlo[3], flo[3];
#pragma unroll
  for (int p = 0; p < 3; ++p) {
    const bool at = us[0 * 3 + p] < RATE;
    const bool af = us[2 * 3 + p] < RATE;
    const int ts = (int)floorf(us[1 * 3 + p] * (float)(T - TIME_MASK));
    const int fs = (int)floorf(us[3 * 3 + p] * (float)(F - FREQ_MASK));
    tlo[p] = at ? ts : T;
    flo[p] = af ? fs : F;
  }

  // Within-batch f4 index j = bx*2560 + i*256 + tid.
  // f0 = (j&31)<<2 depends only on tid; t = bx*80 + i*8 + (tid>>5).
  const int f0 = (tid & 31) << 2;
  bool kf[4];
#pragma unroll
  for (int j = 0; j < 4; ++j) {
    const int f = f0 + j;
    kf[j] = !((f >= flo[0] && f < flo[0] + FREQ_MASK) ||
              (f >= flo[1] && f < flo[1] + FREQ_MASK) ||
              (f >= flo[2] && f < flo[2] + FREQ_MASK));
  }
  const int t_base = blockIdx.x * 80 + (tid >> 5);

#pragma unroll
  for (int i = 0; i < ITERS; ++i) {
    const int t = t_base + i * 8;
    const bool kt = !((t >= tlo[0] && t < tlo[0] + TIME_MASK) ||
                      (t >= tlo[1] && t < tlo[1] + TIME_MASK) ||
                      (t >= tlo[2] && t < tlo[2] + TIME_MASK));
    f32x4 r;
    r.x = (kt && kf[0]) ? vv[i].x : 0.0f;
    r.y = (kt && kf[1]) ? vv[i].y : 0.0f;
    r.z = (kt && kf[2]) ? vv[i].z : 0.0f;
    r.w = (kt && kf[3]) ? vv[i].w : 0.0f;
    out[base + i * 256] = r;
  }
}

extern "C" void kernel_launch(void* const* d_in, const int* in_sizes, int n_in,
                              void* d_out, int out_size, void* d_ws, size_t ws_size,
                              hipStream_t stream) {
  const f32x4* x = (const f32x4*)d_in[0];
  f32x4* out = (f32x4*)d_out;
  dim3 grid(PER_BATCH / BLK_CHUNK, B);  // (50, 64)
  specaug_kernel<<<grid, 256, 0, stream>>>(x, out);
}

// Round 8
// 216.215 us; speedup vs baseline: 1.0475x; 1.0475x over previous
//
#include <hip/hip_runtime.h>
#include <stdint.h>

// SpecAugment: out = x * mask, x:(64,1,4000,128) f32.
// Mask params from jax.random.key(1) (threefry2x32, partitionable path),
// computed in-kernel by 12 threads per block into LDS (fused).
// R8: NT LOADS (don't allocate read stream into L3) + PLAIN STORES
// (let L3 absorb the 131 MB write stream, defer writeback past kernel).
// Only untested load/store-hint combination; single change vs R7.

#define RATE 0.5f
#define POLICY 3
#define FREQ_MASK 15
#define TIME_MASK 35
#define B 64
#define T 4000
#define F 128
#define PER_BATCH (T * F / 4)   // 128000 float4
#define ITERS 10
#define BLK_CHUNK (ITERS * 256) // 2560 float4 per block
// grid.x = 128000 / 2560 = 50; t-rows per block = 2560/32 = 80

typedef float f32x4 __attribute__((ext_vector_type(4)));

__device__ __forceinline__ uint32_t rotl32(uint32_t x, int r) {
  return (x << r) | (x >> (32 - r));
}

// Standard Threefry-2x32, 20 rounds (JAX's threefry2x32_p). Verified exact R1.
__device__ __forceinline__ void threefry2x32(uint32_t k0, uint32_t k1,
                                             uint32_t x0, uint32_t x1,
                                             uint32_t* o0, uint32_t* o1) {
  const uint32_t ks2 = k0 ^ k1 ^ 0x1BD11BDAu;
  x0 += k0; x1 += k1;
  x0 += x1; x1 = rotl32(x1, 13); x1 ^= x0;
  x0 += x1; x1 = rotl32(x1, 15); x1 ^= x0;
  x0 += x1; x1 = rotl32(x1, 26); x1 ^= x0;
  x0 += x1; x1 = rotl32(x1,  6); x1 ^= x0;
  x0 += k1; x1 += ks2 + 1u;
  x0 += x1; x1 = rotl32(x1, 17); x1 ^= x0;
  x0 += x1; x1 = rotl32(x1, 29); x1 ^= x0;
  x0 += x1; x1 = rotl32(x1, 16); x1 ^= x0;
  x0 += x1; x1 = rotl32(x1, 24); x1 ^= x0;
  x0 += ks2; x1 += k0 + 2u;
  x0 += x1; x1 = rotl32(x1, 13); x1 ^= x0;
  x0 += x1; x1 = rotl32(x1, 15); x1 ^= x0;
  x0 += x1; x1 = rotl32(x1, 26); x1 ^= x0;
  x0 += x1; x1 = rotl32(x1,  6); x1 ^= x0;
  x0 += k0; x1 += k1 + 3u;
  x0 += x1; x1 = rotl32(x1, 17); x1 ^= x0;
  x0 += x1; x1 = rotl32(x1, 29); x1 ^= x0;
  x0 += x1; x1 = rotl32(x1, 16); x1 ^= x0;
  x0 += x1; x1 = rotl32(x1, 24); x1 ^= x0;
  x0 += k1; x1 += ks2 + 4u;
  x0 += x1; x1 = rotl32(x1, 13); x1 ^= x0;
  x0 += x1; x1 = rotl32(x1, 15); x1 ^= x0;
  x0 += x1; x1 = rotl32(x1, 26); x1 ^= x0;
  x0 += x1; x1 = rotl32(x1,  6); x1 ^= x0;
  x0 += ks2; x1 += k0 + 5u;
  *o0 = x0; *o1 = x1;
}

__device__ __forceinline__ float bits_to_uniform(uint32_t bits) {
  uint32_t fb = (bits >> 9) | 0x3f800000u;
  float f = __uint_as_float(fb) - 1.0f;
  return fmaxf(f, 0.0f);
}

// grid = (50, 64), block = 256. Each thread: 10 float4 (block chunk 40 KB).
// Threads 0..11 compute the 12 uniform draws for batch b into LDS.
__global__ __launch_bounds__(256) void specaug_kernel(
    const f32x4* __restrict__ x, f32x4* __restrict__ out) {
  __shared__ float us[12];
  const int b = blockIdx.y;
  const int tid = threadIdx.x;

  // ---- issue ALL 10 loads first, nontemporal (no L3 allocation) ----
  const size_t base = (size_t)b * PER_BATCH + (size_t)blockIdx.x * BLK_CHUNK + tid;
  f32x4 vv[ITERS];
#pragma unroll
  for (int i = 0; i < ITERS; ++i)
    vv[i] = __builtin_nontemporal_load(&x[base + i * 256]);

  // ---- 12 threads: subkey d = enc(key1,(0,d)); draw = enc(subkey,(0,b*3+p)) ----
  if (tid < 12) {
    const int d = tid / 3;          // draw kind
    const int p = tid - d * 3;      // policy
    uint32_t k0, k1, o0, o1;
    threefry2x32(0u, 1u, 0u, (uint32_t)d, &k0, &k1);
    threefry2x32(k0, k1, 0u, (uint32_t)(b * 3 + p), &o0, &o1);
    us[tid] = bits_to_uniform(o0 ^ o1);
  }
  __syncthreads();

  // ---- band boundaries (empty band encoded as start==length) ----
  int tlo[3], flo[3];
#pragma unroll
  for (int p = 0; p < 3; ++p) {
    const bool at = us[0 * 3 + p] < RATE;
    const bool af = us[2 * 3 + p] < RATE;
    const int ts = (int)floorf(us[1 * 3 + p] * (float)(T - TIME_MASK));
    const int fs = (int)floorf(us[3 * 3 + p] * (float)(F - FREQ_MASK));
    tlo[p] = at ? ts : T;
    flo[p] = af ? fs : F;
  }

  // Within-batch f4 index j = bx*2560 + i*256 + tid.
  // f0 = (j&31)<<2 depends only on tid; t = bx*80 + i*8 + (tid>>5).
  const int f0 = (tid & 31) << 2;
  bool kf[4];
#pragma unroll
  for (int j = 0; j < 4; ++j) {
    const int f = f0 + j;
    kf[j] = !((f >= flo[0] && f < flo[0] + FREQ_MASK) ||
              (f >= flo[1] && f < flo[1] + FREQ_MASK) ||
              (f >= flo[2] && f < flo[2] + FREQ_MASK));
  }
  const int t_base = blockIdx.x * 80 + (tid >> 5);

#pragma unroll
  for (int i = 0; i < ITERS; ++i) {
    const int t = t_base + i * 8;
    const bool kt = !((t >= tlo[0] && t < tlo[0] + TIME_MASK) ||
                      (t >= tlo[1] && t < tlo[1] + TIME_MASK) ||
                      (t >= tlo[2] && t < tlo[2] + TIME_MASK));
    f32x4 r;
    r.x = (kt && kf[0]) ? vv[i].x : 0.0f;
    r.y = (kt && kf[1]) ? vv[i].y : 0.0f;
    r.z = (kt && kf[2]) ? vv[i].z : 0.0f;
    r.w = (kt && kf[3]) ? vv[i].w : 0.0f;
    out[base + i * 256] = r;   // plain store: absorb in L3, defer writeback
  }
}

extern "C" void kernel_launch(void* const* d_in, const int* in_sizes, int n_in,
                              void* d_out, int out_size, void* d_ws, size_t ws_size,
                              hipStream_t stream) {
  const f32x4* x = (const f32x4*)d_in[0];
  f32x4* out = (f32x4*)d_out;
  dim3 grid(PER_BATCH / BLK_CHUNK, B);  // (50, 64)
  specaug_kernel<<<grid, 256, 0, stream>>>(x, out);
}